// Round 1
// baseline (151.040 us; speedup 1.0000x reference)
//
#include <hip/hip_runtime.h>

// Problem constants (EdgeAwareMultiHeadAttention)
constexpr int Bb   = 4;
constexpr int Nn   = 256;
constexpr int HID  = 256;
constexpr int Ee   = 64;
constexpr int Hh   = 4;
constexpr int OUTc = 128;   // HID/2
constexpr int Dd   = 32;    // OUT/H
constexpr int AGG  = 260;   // H*(2D+1)

constexpr int MT    = 32;   // m-tile rows per iteration
constexpr int A_LD  = 72;   // bf16 row stride (pad 64->72: 16B aligned, uniform bank quads)
constexpr int KV_LD = 260;  // fp32 row stride for KV tile (pad 256->260)

typedef __attribute__((ext_vector_type(8))) short short8;
typedef __attribute__((ext_vector_type(4))) float floatx4;

__device__ __forceinline__ unsigned short f2bf(float f) {
    union { float f; unsigned u; } x; x.f = f;
    unsigned r = x.u + 0x7FFFu + ((x.u >> 16) & 1u);   // RNE
    return (unsigned short)(r >> 16);
}

__device__ __forceinline__ short8 pack8(floatx4 f0, floatx4 f1) {
    short8 v;
    v[0] = (short)f2bf(f0[0]); v[1] = (short)f2bf(f0[1]);
    v[2] = (short)f2bf(f0[2]); v[3] = (short)f2bf(f0[3]);
    v[4] = (short)f2bf(f1[0]); v[5] = (short)f2bf(f1[1]);
    v[6] = (short)f2bf(f1[2]); v[7] = (short)f2bf(f1[3]);
    return v;
}

__global__ __launch_bounds__(256, 3)
void eama_fused(const float* __restrict__ h_x, const float* __restrict__ h_e,
                const float* __restrict__ h_m, const float* __restrict__ W_Q,
                const float* __restrict__ W_K, const float* __restrict__ W_V,
                const float* __restrict__ W_R, float* __restrict__ out)
{
    __shared__ __align__(16) unsigned short sA[MT * A_LD];   // 4.5 KB  bf16 h_e tile
    __shared__ __align__(16) float sKV[MT * KV_LD];          // 32.5 KB fp32 K|V tile
    __shared__ __align__(16) float sQ[OUTc];
    __shared__ float sSc[MT][4];
    __shared__ float sAt[MT][4];
    __shared__ float sAsum[Hh];
    __shared__ float sRed[2][OUTc];
    __shared__ __align__(16) float sMulti[AGG];

    const int tid  = threadIdx.x;
    const int lane = tid & 63;
    const int wv   = tid >> 6;
    const int bn   = blockIdx.x;          // b*N + n
    const float maskv = h_m[bn];

    // ---- B-operand fragments: columns = [W_K rows | W_V rows], bf16, hoisted to regs ----
    // B[k][n=c]: lane holds col n = c_base + (lane&15), k = (lane>>4)*8 + j  (j=0..7)
    short8 bfrag[4][2];
    {
        const int ncol = lane & 15;
        const int q8   = lane >> 4;
        #pragma unroll
        for (int ct = 0; ct < 4; ++ct) {
            const int c = wv * 64 + ct * 16 + ncol;
            const float* row = (c < OUTc) ? (W_K + c * Ee) : (W_V + (c - OUTc) * Ee);
            #pragma unroll
            for (int ks = 0; ks < 2; ++ks) {
                const int k0 = ks * 32 + q8 * 8;
                floatx4 f0 = *(const floatx4*)(row + k0);
                floatx4 f1 = *(const floatx4*)(row + k0 + 4);
                bfrag[ct][ks] = pack8(f0, f1);
            }
        }
    }

    // ---- q[c] = h_x[bn,:] . W_Q[c,:]  (fp32) ----
    {
        float* sHx = sKV;   // reuse KV buffer before first tile
        sHx[tid] = h_x[bn * HID + tid];
        __syncthreads();
        if (tid < OUTc) {
            const float* wq = W_Q + tid * HID;
            float acc = 0.f;
            #pragma unroll 8
            for (int e = 0; e < HID; e += 4) {
                floatx4 w4 = *(const floatx4*)(wq + e);
                floatx4 x4 = *(const floatx4*)(sHx + e);
                acc += w4[0]*x4[0] + w4[1]*x4[1] + w4[2]*x4[2] + w4[3]*x4[3];
            }
            sQ[tid] = acc;
        }
        __syncthreads();
    }

    float vsum = 0.f, vmax = -3.402823466e38f;
    float asum_acc = 0.f;
    const int hf = tid >> 7;        // m-half for aggregation
    const int cp = tid & 127;       // V component index (0..127)
    const int hd = cp >> 5;         // head of that component

    const float* heb = h_e + (size_t)bn * (Nn * Ee);

    for (int tile = 0; tile < Nn / MT; ++tile) {
        const int m0 = tile * MT;
        __syncthreads();   // prev tile's readers of sKV/sAt are done
        // -- stage A tile: h_e rows m0..m0+31 -> bf16 LDS (fully coalesced 8KB stream) --
        {
            const int r = tid >> 3, blk = tid & 7;
            const float* src = heb + (m0 + r) * Ee + blk * 8;
            floatx4 f0 = *(const floatx4*)(src);
            floatx4 f1 = *(const floatx4*)(src + 4);
            *(short8*)&sA[r * A_LD + blk * 8] = pack8(f0, f1);
        }
        __syncthreads();   // A ready
        // -- MFMA: KV[m][c] = sum_k A[m][k] * Wcat[c][k] --
        {
            const int ncol = lane & 15;
            const int q8   = lane >> 4;
            floatx4 acc[2][4];
            #pragma unroll
            for (int mt = 0; mt < 2; ++mt)
                #pragma unroll
                for (int ct = 0; ct < 4; ++ct)
                    acc[mt][ct] = (floatx4){0.f, 0.f, 0.f, 0.f};
            #pragma unroll
            for (int ks = 0; ks < 2; ++ks) {
                short8 a0 = *(const short8*)&sA[(ncol) * A_LD + ks * 32 + q8 * 8];
                short8 a1 = *(const short8*)&sA[(16 + ncol) * A_LD + ks * 32 + q8 * 8];
                #pragma unroll
                for (int ct = 0; ct < 4; ++ct) {
                    acc[0][ct] = __builtin_amdgcn_mfma_f32_16x16x32_bf16(a0, bfrag[ct][ks], acc[0][ct], 0, 0, 0);
                    acc[1][ct] = __builtin_amdgcn_mfma_f32_16x16x32_bf16(a1, bfrag[ct][ks], acc[1][ct], 0, 0, 0);
                }
            }
            // C layout: col = lane&15, row = (lane>>4)*4 + reg  [m89/m91 verified]
            #pragma unroll
            for (int mt = 0; mt < 2; ++mt) {
                const int rowb = mt * 16 + q8 * 4;
                #pragma unroll
                for (int ct = 0; ct < 4; ++ct) {
                    const int col = wv * 64 + ct * 16 + ncol;
                    #pragma unroll
                    for (int r = 0; r < 4; ++r)
                        sKV[(rowb + r) * KV_LD + col] = acc[mt][ct][r];
                }
            }
        }
        __syncthreads();   // KV ready
        // -- scores[m][h] = q[h,:].K[m,h,:] / sqrt(D) --
        if (tid < 128) {
            const int m = tid & 31, h = tid >> 5;
            const float* kvr = &sKV[m * KV_LD + h * Dd];
            const float* qr  = &sQ[h * Dd];
            float p = 0.f;
            #pragma unroll
            for (int d = 0; d < Dd; d += 4) {
                floatx4 k4 = *(const floatx4*)(kvr + d);
                floatx4 q4 = *(const floatx4*)(qr + d);
                p += k4[0]*q4[0] + k4[1]*q4[1] + k4[2]*q4[2] + k4[3]*q4[3];
            }
            p *= 0.1767766952966369f;   // 1/sqrt(32)
            sSc[m][h] = (maskv != 0.f) ? p : -1e30f;   // h_m masks query rows (all-ones in practice)
        }
        __syncthreads();
        // -- softmax over the 4 HEADS (reference softmaxes axis=1!) --
        if (tid < MT) {
            float s0 = sSc[tid][0], s1 = sSc[tid][1], s2 = sSc[tid][2], s3 = sSc[tid][3];
            float mx = fmaxf(fmaxf(s0, s1), fmaxf(s2, s3));
            float e0 = __expf(s0 - mx), e1 = __expf(s1 - mx);
            float e2 = __expf(s2 - mx), e3 = __expf(s3 - mx);
            float inv = 1.f / (e0 + e1 + e2 + e3);
            sAt[tid][0] = e0 * inv; sAt[tid][1] = e1 * inv;
            sAt[tid][2] = e2 * inv; sAt[tid][3] = e3 * inv;
        }
        __syncthreads();
        // -- aggregate sum/max of attn*V over this tile's m rows --
        #pragma unroll
        for (int mm = 0; mm < MT / 2; ++mm) {
            const int m = hf * (MT / 2) + mm;
            const float a  = sAt[m][hd];
            const float vv = sKV[m * KV_LD + OUTc + cp];
            const float aw = a * vv;
            vsum += aw;
            vmax = fmaxf(vmax, aw);
        }
        if (tid < Hh) {
            #pragma unroll
            for (int m = 0; m < MT; ++m) asum_acc += sAt[m][tid];
        }
    }

    // ---- epilogue: merge halves, build multi[260], out = multi @ W_R^T ----
    __syncthreads();
    if (hf) { sRed[0][cp] = vsum; sRed[1][cp] = vmax; }
    if (tid < Hh) sAsum[tid] = asum_acc + 1e-8f;
    __syncthreads();
    if (tid < OUTc) {
        const float vs = vsum + sRed[0][tid];
        const float vm = fmaxf(vmax, sRed[1][tid]);
        const int h = tid >> 5, d = tid & 31;
        sMulti[h * 65 + d]      = vs / sAsum[h];   // mean = sum / attn_sum
        sMulti[h * 65 + 33 + d] = vm;              // max
        if (tid < Hh) sMulti[tid * 65 + 32] = sAsum[tid];
    }
    __syncthreads();
    if (tid < OUTc) {
        const float* wr = W_R + tid * AGG;
        float acc = 0.f;
        #pragma unroll 5
        for (int j = 0; j < AGG; j += 4) {
            floatx4 w4 = *(const floatx4*)(wr + j);
            floatx4 m4 = *(const floatx4*)(&sMulti[j]);
            acc += w4[0]*m4[0] + w4[1]*m4[1] + w4[2]*m4[2] + w4[3]*m4[3];
        }
        out[bn * OUTc + tid] = acc;
    }
}

extern "C" void kernel_launch(void* const* d_in, const int* in_sizes, int n_in,
                              void* d_out, int out_size, void* d_ws, size_t ws_size,
                              hipStream_t stream) {
    const float* h_x = (const float*)d_in[0];
    const float* h_e = (const float*)d_in[1];
    const float* h_m = (const float*)d_in[2];
    const float* W_Q = (const float*)d_in[3];
    const float* W_K = (const float*)d_in[4];
    const float* W_V = (const float*)d_in[5];
    const float* W_R = (const float*)d_in[6];
    float* out = (float*)d_out;
    eama_fused<<<dim3(Bb * Nn), dim3(256), 0, stream>>>(h_x, h_e, h_m, W_Q, W_K, W_V, W_R, out);
}